// Round 3
// baseline (360.377 us; speedup 1.0000x reference)
//
#include <hip/hip_runtime.h>

// ---------------------------------------------------------------------------
// equinet F* pipeline on MI355X.
// Butterfly state: transposed (row*192+col, b) fp32; lane = batch.
// R3: fused V+H1 (identity perm locality) and M1+M2+M3+G1 (identity perms,
// switch folded into fused read). 16 -> 11 kernels, 9 -> 5 state round-trips.
// Final polar->cartesian GEMM: bf16 MFMA 16x16x32, cart fp32 read once (419MB).
// ---------------------------------------------------------------------------

typedef __attribute__((ext_vector_type(8))) short sx8;
typedef __attribute__((ext_vector_type(4))) float fx4;
typedef __attribute__((ext_vector_type(8))) unsigned short usx8;
typedef __attribute__((ext_vector_type(4))) unsigned short usx4;

__device__ __forceinline__ unsigned short f2bf(float f) {
  unsigned u = __builtin_bit_cast(unsigned, f);
  u = (u + 0x7FFFu + ((u >> 16) & 1u)) >> 16;   // round-to-nearest-even
  return (unsigned short)u;
}
__device__ __forceinline__ float bf2f(unsigned short h) {
  return __builtin_bit_cast(float, ((unsigned)h) << 16);
}

// Permutation ids: 0=identity, 1=perm(l=4), 2=perm(l=3), 3=switch(8x8 transpose),
// 4=perm(l=2), 5=perm(l=1), 6=perm(l=0).  (perm(l=5) == identity.)
template<int ID>
__device__ __forceinline__ int rp_apply(int k) {
  if constexpr (ID == 0) { return k; }
  else if constexpr (ID == 3) { return (k & 7) * 8 + (k >> 3); }
  else {
    constexpr int l = (ID == 1) ? 4 : (ID == 2) ? 3 : (ID == 4) ? 2 : (ID == 5) ? 1 : 0;
    constexpr int d = 1 << (5 - l);
    constexpr int m2 = 2 * d;
    int g = k / m2, r = k % m2;
    return g * m2 + (r & 1) * d + (r >> 1);
  }
}

// ---------------------------------------------------------------------------
// Transpose x (B,128,128,2) -> xtr/xti (16384, 128)
// ---------------------------------------------------------------------------
__global__ __launch_bounds__(256) void k_transpose(const float* __restrict__ x,
                                                   float* __restrict__ xtr,
                                                   float* __restrict__ xti) {
  __shared__ float ls[2][32][129];
  const int t = threadIdx.x;
  const int u = blockIdx.x;         // row 0..127
  const int v0 = blockIdx.y * 32;   // col chunk
  for (int it = 0; it < 32; ++it) {
    int b = it * 4 + (t >> 6);
    int r = t & 63;
    int v = r >> 1, ch = r & 1;
    ls[ch][v][b] = x[(((size_t)b * 128 + u) * 128 + (v0 + v)) * 2 + ch];
  }
  __syncthreads();
  for (int it = 0; it < 32; ++it) {
    int idx = it * 256 + t;
    int ch = idx >> 12;
    int v = (idx >> 7) & 31;
    int b = idx & 127;
    float* dst = ch ? xti : xtr;
    dst[((size_t)(u * 128 + v0 + v)) * 128 + b] = ls[ch][v][b];
  }
}

// ---------------------------------------------------------------------------
// Fused V + H1 (H1 perm is identity).  Grid (32,32), 128 threads (lane=batch).
// vp: (8,64,2,3), hp: (8,32,6,6).
// ---------------------------------------------------------------------------
__global__ __launch_bounds__(128) void k_vh(const float* __restrict__ xtr,
                                            const float* __restrict__ xti,
                                            float* __restrict__ yr,
                                            float* __restrict__ yi,
                                            const float* __restrict__ vp,
                                            const float* __restrict__ hp) {
  const int b = threadIdx.x;
  const int P = blockIdx.x, Q = blockIdx.y;
  float Vr[36], Vi[36];

  // ---- V stage: 4 sub-blocks (pp,qq) -> fills the 6x6 (Vr,Vi) tile ----
#pragma unroll
  for (int pp = 0; pp < 2; ++pp)
#pragma unroll
    for (int qq = 0; qq < 2; ++qq) {
      const int p = 2 * P + pp, q = 2 * Q + qq;
      float Xr[4], Xi[4];
#pragma unroll
      for (int i = 0; i < 2; ++i)
#pragma unroll
        for (int j = 0; j < 2; ++j) {
          size_t off = ((size_t)((4 * P + 2 * pp + i) * 128 + (4 * Q + 2 * qq + j))) * 128 + b;
          Xr[i * 2 + j] = xtr[off];
          Xi[i * 2 + j] = xti[off];
        }
      float Ar[9], Ai[9];
#pragma unroll
      for (int k = 0; k < 9; ++k) { Ar[k] = 0.f; Ai[k] = 0.f; }
      auto termV = [&](float* Y, const float* X, int lm, int rm) {
        const float* Lw = vp + ((size_t)lm * 64 + p) * 6;  // (2,3)
        const float* Rw = vp + ((size_t)rm * 64 + q) * 6;
#pragma unroll
        for (int i = 0; i < 2; ++i) {
          float t0 = X[i*2+0] * Rw[0] + X[i*2+1] * Rw[3];
          float t1 = X[i*2+0] * Rw[1] + X[i*2+1] * Rw[4];
          float t2 = X[i*2+0] * Rw[2] + X[i*2+1] * Rw[5];
#pragma unroll
          for (int o = 0; o < 3; ++o) {
            float lv = Lw[i * 3 + o];
            Y[o*3+0] += lv * t0; Y[o*3+1] += lv * t1; Y[o*3+2] += lv * t2;
          }
        }
      };
      termV(Ar, Xr, 0, 0); termV(Ar, Xr, 1, 1); termV(Ai, Xr, 6, 7); termV(Ai, Xr, 7, 6);
      termV(Ar, Xi, 2, 3); termV(Ar, Xi, 3, 2); termV(Ai, Xi, 4, 4); termV(Ai, Xi, 5, 5);
#pragma unroll
      for (int o = 0; o < 3; ++o)
#pragma unroll
        for (int k = 0; k < 3; ++k) {
          Vr[(3 * pp + o) * 6 + 3 * qq + k] = Ar[o * 3 + k];
          Vi[(3 * pp + o) * 6 + 3 * qq + k] = Ai[o * 3 + k];
        }
    }

  // ---- H1 stage on the register-resident 6x6 tile ----
  float Yr[36], Yi[36];
#pragma unroll
  for (int k = 0; k < 36; ++k) { Yr[k] = 0.f; Yi[k] = 0.f; }
  auto termH = [&](float* Y, const float* X, int lm, int rm) {
    const float* Lw = hp + ((size_t)lm * 32 + P) * 36;
    const float* Rw = hp + ((size_t)rm * 32 + Q) * 36;
#pragma unroll
    for (int i = 0; i < 6; ++i) {
      float tk[6];
#pragma unroll
      for (int k = 0; k < 6; ++k) tk[k] = 0.f;
#pragma unroll
      for (int j = 0; j < 6; ++j) {
        float xv = X[i * 6 + j];
#pragma unroll
        for (int k = 0; k < 6; ++k) tk[k] += xv * Rw[j * 6 + k];
      }
#pragma unroll
      for (int o = 0; o < 6; ++o) {
        float lv = Lw[i * 6 + o];
#pragma unroll
        for (int k = 0; k < 6; ++k) Y[o * 6 + k] += lv * tk[k];
      }
    }
  };
  termH(Yr, Vr, 0, 0); termH(Yr, Vr, 1, 1); termH(Yi, Vr, 6, 7); termH(Yi, Vr, 7, 6);
  termH(Yr, Vi, 2, 3); termH(Yr, Vi, 3, 2); termH(Yi, Vi, 4, 4); termH(Yi, Vi, 5, 5);

#pragma unroll
  for (int I = 0; I < 6; ++I)
#pragma unroll
    for (int J = 0; J < 6; ++J) {
      size_t off = ((size_t)((P * 6 + I) * 192 + (Q * 6 + J))) * 128 + b;
      yr[off] = Yr[I * 6 + J];
      yi[off] = Yi[I * 6 + J];
    }
}

// ---------------------------------------------------------------------------
// H/G layer: merged 32 blocks of 6x6; PERM applied (at 64-block level) on read.
// wp: (8,32,6,6).  128 threads (lane=batch).
// ---------------------------------------------------------------------------
template<int PERM>
__global__ __launch_bounds__(128) void k_hg(const float* __restrict__ xr,
                                            const float* __restrict__ xi,
                                            float* __restrict__ yr,
                                            float* __restrict__ yi,
                                            const float* __restrict__ wp) {
  const int b = threadIdx.x;
  const int P = blockIdx.x, Q = blockIdx.y;
  int rrow[6], rcol[6];
#pragma unroll
  for (int I = 0; I < 6; ++I) {
    rrow[I] = rp_apply<PERM>(2 * P + I / 3) * 3 + I % 3;
    rcol[I] = rp_apply<PERM>(2 * Q + I / 3) * 3 + I % 3;
  }
  float X[36], Yr[36], Yi[36];
#pragma unroll
  for (int k = 0; k < 36; ++k) { Yr[k] = 0.f; Yi[k] = 0.f; }

  auto loadX = [&](const float* src) {
#pragma unroll
    for (int I = 0; I < 6; ++I)
#pragma unroll
      for (int J = 0; J < 6; ++J)
        X[I * 6 + J] = src[((size_t)(rrow[I] * 192 + rcol[J])) * 128 + b];
  };
  auto term = [&](float* Y, int lm, int rm) {
    const float* Lw = wp + ((size_t)lm * 32 + P) * 36;
    const float* Rw = wp + ((size_t)rm * 32 + Q) * 36;
#pragma unroll
    for (int i = 0; i < 6; ++i) {
      float tk[6];
#pragma unroll
      for (int k = 0; k < 6; ++k) tk[k] = 0.f;
#pragma unroll
      for (int j = 0; j < 6; ++j) {
        float xv = X[i * 6 + j];
#pragma unroll
        for (int k = 0; k < 6; ++k) tk[k] += xv * Rw[j * 6 + k];
      }
#pragma unroll
      for (int o = 0; o < 6; ++o) {
        float lv = Lw[i * 6 + o];
#pragma unroll
        for (int k = 0; k < 6; ++k) Y[o * 6 + k] += lv * tk[k];
      }
    }
  };
  loadX(xr);
  term(Yr, 0, 0); term(Yr, 1, 1); term(Yi, 6, 7); term(Yi, 7, 6);
  loadX(xi);
  term(Yr, 2, 3); term(Yr, 3, 2); term(Yi, 4, 4); term(Yi, 5, 5);
#pragma unroll
  for (int I = 0; I < 6; ++I)
#pragma unroll
    for (int J = 0; J < 6; ++J) {
      size_t off = ((size_t)((P * 6 + I) * 192 + (Q * 6 + J))) * 128 + b;
      yr[off] = Yr[I * 6 + J];
      yi[off] = Yi[I * 6 + J];
    }
}

// ---------------------------------------------------------------------------
// Fused M1+M2+M3+G1.  M1 reads with switch perm; M2/M3/G1 identity.
// Grid (32,32), 128 threads. mp: (3,8,64,3,3), gp: (8,32,6,6) (stage 0).
// ---------------------------------------------------------------------------
__global__ __launch_bounds__(128) void k_mg(const float* __restrict__ xr,
                                            const float* __restrict__ xi,
                                            float* __restrict__ yr,
                                            float* __restrict__ yi,
                                            const float* __restrict__ mp,
                                            const float* __restrict__ gp) {
  const int b = threadIdx.x;
  const int P = blockIdx.x, Q = blockIdx.y;
  float Vr[36], Vi[36];

#pragma unroll
  for (int aa = 0; aa < 2; ++aa)
#pragma unroll
    for (int bb = 0; bb < 2; ++bb) {
      const int p = 2 * P + aa, q = 2 * Q + bb;
      const int prow = rp_apply<3>(p) * 3, pcol = rp_apply<3>(q) * 3;
      float Xr[9], Xi[9];
#pragma unroll
      for (int i = 0; i < 3; ++i)
#pragma unroll
        for (int j = 0; j < 3; ++j) {
          size_t off = ((size_t)((prow + i) * 192 + (pcol + j))) * 128 + b;
          Xr[i * 3 + j] = xr[off];
          Xi[i * 3 + j] = xi[off];
        }
      // 3 residual M layers in registers
#pragma unroll
      for (int lk = 0; lk < 3; ++lk) {
        const float* wp = mp + (size_t)lk * (8 * 64 * 9);
        float Yr9[9], Yi9[9];
#pragma unroll
        for (int k = 0; k < 9; ++k) { Yr9[k] = Xr[k]; Yi9[k] = Xi[k]; }
        auto termM = [&](float* Y, const float* X, int lm, int rm) {
          const float* Lw = wp + ((size_t)lm * 64 + p) * 9;
          const float* Rw = wp + ((size_t)rm * 64 + q) * 9;
#pragma unroll
          for (int i = 0; i < 3; ++i) {
            float t0 = X[i*3+0] * Rw[0] + X[i*3+1] * Rw[3] + X[i*3+2] * Rw[6];
            float t1 = X[i*3+0] * Rw[1] + X[i*3+1] * Rw[4] + X[i*3+2] * Rw[7];
            float t2 = X[i*3+0] * Rw[2] + X[i*3+1] * Rw[5] + X[i*3+2] * Rw[8];
#pragma unroll
            for (int o = 0; o < 3; ++o) {
              float lv = Lw[i * 3 + o];
              Y[o*3+0] += lv * t0; Y[o*3+1] += lv * t1; Y[o*3+2] += lv * t2;
            }
          }
        };
        termM(Yr9, Xr, 0, 0); termM(Yr9, Xr, 1, 1); termM(Yi9, Xr, 6, 7); termM(Yi9, Xr, 7, 6);
        termM(Yr9, Xi, 2, 3); termM(Yr9, Xi, 3, 2); termM(Yi9, Xi, 4, 4); termM(Yi9, Xi, 5, 5);
#pragma unroll
        for (int k = 0; k < 9; ++k) { Xr[k] = Yr9[k]; Xi[k] = Yi9[k]; }
      }
#pragma unroll
      for (int i = 0; i < 3; ++i)
#pragma unroll
        for (int j = 0; j < 3; ++j) {
          Vr[(3 * aa + i) * 6 + 3 * bb + j] = Xr[i * 3 + j];
          Vi[(3 * aa + i) * 6 + 3 * bb + j] = Xi[i * 3 + j];
        }
    }

  // ---- G1 on register-resident 6x6 tile ----
  float Yr[36], Yi[36];
#pragma unroll
  for (int k = 0; k < 36; ++k) { Yr[k] = 0.f; Yi[k] = 0.f; }
  auto termH = [&](float* Y, const float* X, int lm, int rm) {
    const float* Lw = gp + ((size_t)lm * 32 + P) * 36;
    const float* Rw = gp + ((size_t)rm * 32 + Q) * 36;
#pragma unroll
    for (int i = 0; i < 6; ++i) {
      float tk[6];
#pragma unroll
      for (int k = 0; k < 6; ++k) tk[k] = 0.f;
#pragma unroll
      for (int j = 0; j < 6; ++j) {
        float xv = X[i * 6 + j];
#pragma unroll
        for (int k = 0; k < 6; ++k) tk[k] += xv * Rw[j * 6 + k];
      }
#pragma unroll
      for (int o = 0; o < 6; ++o) {
        float lv = Lw[i * 6 + o];
#pragma unroll
        for (int k = 0; k < 6; ++k) Y[o * 6 + k] += lv * tk[k];
      }
    }
  };
  termH(Yr, Vr, 0, 0); termH(Yr, Vr, 1, 1); termH(Yi, Vr, 6, 7); termH(Yi, Vr, 7, 6);
  termH(Yr, Vi, 2, 3); termH(Yr, Vi, 3, 2); termH(Yi, Vi, 4, 4); termH(Yi, Vi, 5, 5);

#pragma unroll
  for (int I = 0; I < 6; ++I)
#pragma unroll
    for (int J = 0; J < 6; ++J) {
      size_t off = ((size_t)((P * 6 + I) * 192 + (Q * 6 + J))) * 128 + b;
      yr[off] = Yr[I * 6 + J];
      yi[off] = Yi[I * 6 + J];
    }
}

// ---------------------------------------------------------------------------
// U layer: Sin=3 -> Sout=2, real bf16 output. perm(l=0) on read. Up: (8,64,3,2)
// out ut: (16384, 128) bf16
// ---------------------------------------------------------------------------
__global__ __launch_bounds__(128) void k_u(const float* __restrict__ xr,
                                           const float* __restrict__ xi,
                                           unsigned short* __restrict__ ut,
                                           const float* __restrict__ wp) {
  const int b = threadIdx.x;
  const int p = blockIdx.x, q = blockIdx.y;
  int rrow[3], rcol[3];
#pragma unroll
  for (int i = 0; i < 3; ++i) {
    rrow[i] = rp_apply<6>(p) * 3 + i;
    rcol[i] = rp_apply<6>(q) * 3 + i;
  }
  float X[9], Y[4] = {0.f, 0.f, 0.f, 0.f};
  auto loadX = [&](const float* src) {
#pragma unroll
    for (int i = 0; i < 3; ++i)
#pragma unroll
      for (int j = 0; j < 3; ++j)
        X[i * 3 + j] = src[((size_t)(rrow[i] * 192 + rcol[j])) * 128 + b];
  };
  auto term = [&](int lm, int rm) {
    const float* Lw = wp + ((size_t)lm * 64 + p) * 6;  // (3,2)
    const float* Rw = wp + ((size_t)rm * 64 + q) * 6;
#pragma unroll
    for (int i = 0; i < 3; ++i) {
      float t0 = X[i*3+0] * Rw[0] + X[i*3+1] * Rw[2] + X[i*3+2] * Rw[4];
      float t1 = X[i*3+0] * Rw[1] + X[i*3+1] * Rw[3] + X[i*3+2] * Rw[5];
      Y[0] += Lw[i*2+0] * t0; Y[1] += Lw[i*2+0] * t1;
      Y[2] += Lw[i*2+1] * t0; Y[3] += Lw[i*2+1] * t1;
    }
  };
  loadX(xr); term(0, 0); term(3, 3);     // (ur1,ur1), (ui2,ui2) on xr
  loadX(xi); term(4, 5); term(7, 6);     // (ur3,ui3), (ui4,ur4) on xi
#pragma unroll
  for (int o = 0; o < 2; ++o)
#pragma unroll
    for (int k = 0; k < 2; ++k)
      ut[((size_t)((p * 2 + o) * 128 + (q * 2 + k))) * 128 + b] = f2bf(Y[o * 2 + k]);
}

// ---------------------------------------------------------------------------
// Gather + transpose: yg[b][m] = ut[r_index[m]][b]; both bf16. yg (128,16384)
// ---------------------------------------------------------------------------
__global__ __launch_bounds__(256) void k_gather(const unsigned short* __restrict__ ut,
                                                const int* __restrict__ r_index,
                                                unsigned short* __restrict__ yg) {
  __shared__ unsigned short ls[64][130];
  __shared__ int ridx[64];
  const int t = threadIdx.x;
  const int m0 = blockIdx.x * 64;
  if (t < 64) ridx[t] = r_index[m0 + t];
  __syncthreads();
  for (int it = 0; it < 32; ++it) {
    int idx = it * 256 + t;
    int ml = idx >> 7, b = idx & 127;
    ls[ml][b] = ut[(size_t)ridx[ml] * 128 + b];
  }
  __syncthreads();
  int b = t >> 1, half = t & 1;
#pragma unroll
  for (int c = 0; c < 4; ++c) {
    usx8 v;
#pragma unroll
    for (int e = 0; e < 8; ++e) v[e] = ls[half * 32 + c * 8 + e][b];
    *(usx8*)(yg + (size_t)b * 16384 + m0 + half * 32 + c * 8) = v;
  }
}

// ---------------------------------------------------------------------------
// GEMM: out[b][c] = sum_k yg[b][k] * cart[c][k].  M=128, N=6400, K=16384.
// Tile: 128x128, K split into 16 chunks of 1024 -> partial (16,128,6400) bf16.
// ---------------------------------------------------------------------------
#define GEMM_KC 16
#define GEMM_NKS 32   // (16384/16)/32

__global__ __launch_bounds__(256) void k_gemm(const unsigned short* __restrict__ yg,
                                              const float* __restrict__ cart,
                                              unsigned short* __restrict__ partial) {
  __shared__ unsigned short As[2][128][40];  // 80B pitch: conflict-free b128 reads
  __shared__ unsigned short Bs[2][128][40];
  const int t = threadIdx.x;
  const int lane = t & 63, w = t >> 6;
  const int wm = w >> 1, wn = w & 1;           // 2x2 waves, each 64x64 out
  const int c0 = blockIdx.x * 128;
  const int k0 = blockIdx.y * 1024;
  const int kc = blockIdx.y;

  fx4 acc[4][4];
#pragma unroll
  for (int i = 0; i < 4; ++i)
#pragma unroll
    for (int j = 0; j < 4; ++j) acc[i][j] = (fx4)0.f;

  auto ldA = [&](int rep, int kpos) -> usx8 {
    int c = t + rep * 256;
    return *(const usx8*)(yg + (size_t)(c >> 2) * 16384 + kpos + (c & 3) * 8);
  };
  auto stA = [&](int buf, int rep, usx8 v) {
    int c = t + rep * 256;
    *(usx8*)(&As[buf][c >> 2][(c & 3) * 8]) = v;
  };
  auto ldB = [&](int rep, int kpos) -> fx4 {
    int c = t + rep * 256;
    return *(const fx4*)(cart + (size_t)(c0 + (c >> 3)) * 16384 + kpos + (c & 7) * 4);
  };
  auto stB = [&](int buf, int rep, fx4 f) {
    int c = t + rep * 256;
    usx4 v;
    v[0] = f2bf(f[0]); v[1] = f2bf(f[1]); v[2] = f2bf(f[2]); v[3] = f2bf(f[3]);
    *(usx4*)(&Bs[buf][c >> 3][(c & 7) * 4]) = v;
  };

  { // prologue: stage step 0 into buf 0
    usx8 a0 = ldA(0, k0), a1 = ldA(1, k0);
    fx4 b0 = ldB(0, k0), b1 = ldB(1, k0), b2 = ldB(2, k0), b3 = ldB(3, k0);
    stA(0, 0, a0); stA(0, 1, a1);
    stB(0, 0, b0); stB(0, 1, b1); stB(0, 2, b2); stB(0, 3, b3);
  }
  __syncthreads();

  for (int s = 0; s < GEMM_NKS; ++s) {
    const int cur = s & 1;
    usx8 av0, av1; fx4 bv0, bv1, bv2, bv3;
    const bool pf = (s + 1 < GEMM_NKS);
    if (pf) {           // issue next-step global loads early
      int kpos = k0 + (s + 1) * 32;
      av0 = ldA(0, kpos); av1 = ldA(1, kpos);
      bv0 = ldB(0, kpos); bv1 = ldB(1, kpos); bv2 = ldB(2, kpos); bv3 = ldB(3, kpos);
    }
    // compute on current buffer
    sx8 af[4], bfr[4];
#pragma unroll
    for (int mi = 0; mi < 4; ++mi) {
      int row = wm * 64 + mi * 16 + (lane & 15);
      af[mi] = *(const sx8*)(&As[cur][row][(lane >> 4) * 8]);
    }
#pragma unroll
    for (int ni = 0; ni < 4; ++ni) {
      int row = wn * 64 + ni * 16 + (lane & 15);
      bfr[ni] = *(const sx8*)(&Bs[cur][row][(lane >> 4) * 8]);
    }
#pragma unroll
    for (int mi = 0; mi < 4; ++mi)
#pragma unroll
      for (int ni = 0; ni < 4; ++ni)
        acc[mi][ni] = __builtin_amdgcn_mfma_f32_16x16x32_bf16(af[mi], bfr[ni], acc[mi][ni], 0, 0, 0);
    if (pf) {           // write-back staged data (after compute)
      stA(cur ^ 1, 0, av0); stA(cur ^ 1, 1, av1);
      stB(cur ^ 1, 0, bv0); stB(cur ^ 1, 1, bv1); stB(cur ^ 1, 2, bv2); stB(cur ^ 1, 3, bv3);
    }
    __syncthreads();
  }

  // epilogue: partial[kc][b][c] in bf16
#pragma unroll
  for (int mi = 0; mi < 4; ++mi) {
    int brow = wm * 64 + mi * 16 + (lane >> 4) * 4;
#pragma unroll
    for (int ni = 0; ni < 4; ++ni) {
      int cc = c0 + wn * 64 + ni * 16 + (lane & 15);
#pragma unroll
      for (int r = 0; r < 4; ++r)
        partial[((size_t)kc * 128 + brow + r) * 6400 + cc] = f2bf(acc[mi][ni][r]);
    }
  }
}

__global__ __launch_bounds__(256) void k_reduce(const unsigned short* __restrict__ partial,
                                                float* __restrict__ out) {
  int i = blockIdx.x * 256 + threadIdx.x;   // group of 4 floats, 204800 total
  fx4 s = (fx4)0.f;
#pragma unroll
  for (int kc = 0; kc < GEMM_KC; ++kc) {
    usx4 v = *(const usx4*)(partial + (size_t)kc * 819200 + (size_t)i * 4);
    s[0] += bf2f(v[0]); s[1] += bf2f(v[1]); s[2] += bf2f(v[2]); s[3] += bf2f(v[3]);
  }
  *(fx4*)(out + (size_t)i * 4) = s;
}

// ---------------------------------------------------------------------------
extern "C" void kernel_launch(void* const* d_in, const int* in_sizes, int n_in,
                              void* d_out, int out_size, void* d_ws, size_t ws_size,
                              hipStream_t stream) {
  const float* x    = (const float*)d_in[0];
  const float* Vp   = (const float*)d_in[1];
  const float* Hp   = (const float*)d_in[2];
  const float* Mp   = (const float*)d_in[3];
  const float* Gp   = (const float*)d_in[4];
  const float* Up   = (const float*)d_in[5];
  const float* cart = (const float*)d_in[6];
  const int*   ridx = (const int*)d_in[7];
  float* out = (float*)d_out;
  float* ws  = (float*)d_ws;

  const size_t PSZ = 4718592;              // 36864*128 floats (18.87 MB)
  float* P0r = ws;
  float* P0i = ws + PSZ;
  float* P1r = ws + 2 * PSZ;
  float* P1i = ws + 3 * PSZ;
  float* xtr = ws + 4 * PSZ;               // 2097152 floats, dead after k_vh
  float* xti = xtr + 2097152;              // dead after k_vh
  unsigned short* ut = (unsigned short*)(ws + 4 * PSZ);            // reuses xtr (bf16)
  unsigned short* yg = (unsigned short*)(ws + 4 * PSZ + 1048576);  // after ut
  unsigned short* partial = (unsigned short*)ws;  // 16*819200 bf16 (26 MB), reuses P0 (dead)

  const size_t HSZ = 8 * 32 * 36;          // one H/G stage's params

  k_transpose<<<dim3(128, 4), 256, 0, stream>>>(x, xtr, xti);
  k_vh<<<dim3(32, 32), 128, 0, stream>>>(xtr, xti, P0r, P0i, Vp, Hp + 0 * HSZ);
  k_hg<1><<<dim3(32, 32), 128, 0, stream>>>(P0r, P0i, P1r, P1i, Hp + 1 * HSZ);  // perm(l=4)
  k_hg<2><<<dim3(32, 32), 128, 0, stream>>>(P1r, P1i, P0r, P0i, Hp + 2 * HSZ);  // perm(l=3)
  k_mg<<<dim3(32, 32), 128, 0, stream>>>(P0r, P0i, P1r, P1i, Mp, Gp + 0 * HSZ); // switch+M123+G1
  k_hg<4><<<dim3(32, 32), 128, 0, stream>>>(P1r, P1i, P0r, P0i, Gp + 1 * HSZ);  // perm(l=2)
  k_hg<5><<<dim3(32, 32), 128, 0, stream>>>(P0r, P0i, P1r, P1i, Gp + 2 * HSZ);  // perm(l=1)
  k_u<<<dim3(64, 64), 128, 0, stream>>>(P1r, P1i, ut, Up);                      // perm(l=0) inside
  k_gather<<<dim3(256), 256, 0, stream>>>(ut, ridx, yg);
  k_gemm<<<dim3(50, GEMM_KC), 256, 0, stream>>>(yg, cart, partial);
  k_reduce<<<dim3(800), 256, 0, stream>>>(partial, out);
  (void)in_sizes; (void)n_in; (void)out_size; (void)ws_size;
}

// Round 4
// 342.405 us; speedup vs baseline: 1.0525x; 1.0525x over previous
//
#include <hip/hip_runtime.h>

// ---------------------------------------------------------------------------
// equinet F* pipeline on MI355X.
// Butterfly state: transposed (row*192+col, b) fp32; lane = batch.
// R4: GEMM rebuilt for DRAM locality — c-tile 64, k-split 4, BK=64 so each
// cart row is consumed in 256B contiguous runs by 4 cooperating WGs instead
// of 128B quanta interleaved across 128 rows x 800 WGs (page-thrash fix).
// ---------------------------------------------------------------------------

typedef __attribute__((ext_vector_type(8))) short sx8;
typedef __attribute__((ext_vector_type(4))) float fx4;
typedef __attribute__((ext_vector_type(8))) unsigned short usx8;
typedef __attribute__((ext_vector_type(4))) unsigned short usx4;

__device__ __forceinline__ unsigned short f2bf(float f) {
  unsigned u = __builtin_bit_cast(unsigned, f);
  u = (u + 0x7FFFu + ((u >> 16) & 1u)) >> 16;   // round-to-nearest-even
  return (unsigned short)u;
}
__device__ __forceinline__ float bf2f(unsigned short h) {
  return __builtin_bit_cast(float, ((unsigned)h) << 16);
}

// Permutation ids: 0=identity, 1=perm(l=4), 2=perm(l=3), 3=switch(8x8 transpose),
// 4=perm(l=2), 5=perm(l=1), 6=perm(l=0).  (perm(l=5) == identity.)
template<int ID>
__device__ __forceinline__ int rp_apply(int k) {
  if constexpr (ID == 0) { return k; }
  else if constexpr (ID == 3) { return (k & 7) * 8 + (k >> 3); }
  else {
    constexpr int l = (ID == 1) ? 4 : (ID == 2) ? 3 : (ID == 4) ? 2 : (ID == 5) ? 1 : 0;
    constexpr int d = 1 << (5 - l);
    constexpr int m2 = 2 * d;
    int g = k / m2, r = k % m2;
    return g * m2 + (r & 1) * d + (r >> 1);
  }
}

// ---------------------------------------------------------------------------
// Transpose x (B,128,128,2) -> xtr/xti (16384, 128)
// ---------------------------------------------------------------------------
__global__ __launch_bounds__(256) void k_transpose(const float* __restrict__ x,
                                                   float* __restrict__ xtr,
                                                   float* __restrict__ xti) {
  __shared__ float ls[2][32][129];
  const int t = threadIdx.x;
  const int u = blockIdx.x;         // row 0..127
  const int v0 = blockIdx.y * 32;   // col chunk
  for (int it = 0; it < 32; ++it) {
    int b = it * 4 + (t >> 6);
    int r = t & 63;
    int v = r >> 1, ch = r & 1;
    ls[ch][v][b] = x[(((size_t)b * 128 + u) * 128 + (v0 + v)) * 2 + ch];
  }
  __syncthreads();
  for (int it = 0; it < 32; ++it) {
    int idx = it * 256 + t;
    int ch = idx >> 12;
    int v = (idx >> 7) & 31;
    int b = idx & 127;
    float* dst = ch ? xti : xtr;
    dst[((size_t)(u * 128 + v0 + v)) * 128 + b] = ls[ch][v][b];
  }
}

// ---------------------------------------------------------------------------
// Fused V + H1 (H1 perm is identity).  Grid (32,32), 128 threads (lane=batch).
// vp: (8,64,2,3), hp: (8,32,6,6).
// ---------------------------------------------------------------------------
__global__ __launch_bounds__(128) void k_vh(const float* __restrict__ xtr,
                                            const float* __restrict__ xti,
                                            float* __restrict__ yr,
                                            float* __restrict__ yi,
                                            const float* __restrict__ vp,
                                            const float* __restrict__ hp) {
  const int b = threadIdx.x;
  const int P = blockIdx.x, Q = blockIdx.y;
  float Vr[36], Vi[36];

#pragma unroll
  for (int pp = 0; pp < 2; ++pp)
#pragma unroll
    for (int qq = 0; qq < 2; ++qq) {
      const int p = 2 * P + pp, q = 2 * Q + qq;
      float Xr[4], Xi[4];
#pragma unroll
      for (int i = 0; i < 2; ++i)
#pragma unroll
        for (int j = 0; j < 2; ++j) {
          size_t off = ((size_t)((4 * P + 2 * pp + i) * 128 + (4 * Q + 2 * qq + j))) * 128 + b;
          Xr[i * 2 + j] = xtr[off];
          Xi[i * 2 + j] = xti[off];
        }
      float Ar[9], Ai[9];
#pragma unroll
      for (int k = 0; k < 9; ++k) { Ar[k] = 0.f; Ai[k] = 0.f; }
      auto termV = [&](float* Y, const float* X, int lm, int rm) {
        const float* Lw = vp + ((size_t)lm * 64 + p) * 6;  // (2,3)
        const float* Rw = vp + ((size_t)rm * 64 + q) * 6;
#pragma unroll
        for (int i = 0; i < 2; ++i) {
          float t0 = X[i*2+0] * Rw[0] + X[i*2+1] * Rw[3];
          float t1 = X[i*2+0] * Rw[1] + X[i*2+1] * Rw[4];
          float t2 = X[i*2+0] * Rw[2] + X[i*2+1] * Rw[5];
#pragma unroll
          for (int o = 0; o < 3; ++o) {
            float lv = Lw[i * 3 + o];
            Y[o*3+0] += lv * t0; Y[o*3+1] += lv * t1; Y[o*3+2] += lv * t2;
          }
        }
      };
      termV(Ar, Xr, 0, 0); termV(Ar, Xr, 1, 1); termV(Ai, Xr, 6, 7); termV(Ai, Xr, 7, 6);
      termV(Ar, Xi, 2, 3); termV(Ar, Xi, 3, 2); termV(Ai, Xi, 4, 4); termV(Ai, Xi, 5, 5);
#pragma unroll
      for (int o = 0; o < 3; ++o)
#pragma unroll
        for (int k = 0; k < 3; ++k) {
          Vr[(3 * pp + o) * 6 + 3 * qq + k] = Ar[o * 3 + k];
          Vi[(3 * pp + o) * 6 + 3 * qq + k] = Ai[o * 3 + k];
        }
    }

  float Yr[36], Yi[36];
#pragma unroll
  for (int k = 0; k < 36; ++k) { Yr[k] = 0.f; Yi[k] = 0.f; }
  auto termH = [&](float* Y, const float* X, int lm, int rm) {
    const float* Lw = hp + ((size_t)lm * 32 + P) * 36;
    const float* Rw = hp + ((size_t)rm * 32 + Q) * 36;
#pragma unroll
    for (int i = 0; i < 6; ++i) {
      float tk[6];
#pragma unroll
      for (int k = 0; k < 6; ++k) tk[k] = 0.f;
#pragma unroll
      for (int j = 0; j < 6; ++j) {
        float xv = X[i * 6 + j];
#pragma unroll
        for (int k = 0; k < 6; ++k) tk[k] += xv * Rw[j * 6 + k];
      }
#pragma unroll
      for (int o = 0; o < 6; ++o) {
        float lv = Lw[i * 6 + o];
#pragma unroll
        for (int k = 0; k < 6; ++k) Y[o * 6 + k] += lv * tk[k];
      }
    }
  };
  termH(Yr, Vr, 0, 0); termH(Yr, Vr, 1, 1); termH(Yi, Vr, 6, 7); termH(Yi, Vr, 7, 6);
  termH(Yr, Vi, 2, 3); termH(Yr, Vi, 3, 2); termH(Yi, Vi, 4, 4); termH(Yi, Vi, 5, 5);

#pragma unroll
  for (int I = 0; I < 6; ++I)
#pragma unroll
    for (int J = 0; J < 6; ++J) {
      size_t off = ((size_t)((P * 6 + I) * 192 + (Q * 6 + J))) * 128 + b;
      yr[off] = Yr[I * 6 + J];
      yi[off] = Yi[I * 6 + J];
    }
}

// ---------------------------------------------------------------------------
// H/G layer: merged 32 blocks of 6x6; PERM applied (at 64-block level) on read.
// wp: (8,32,6,6).  128 threads (lane=batch).
// ---------------------------------------------------------------------------
template<int PERM>
__global__ __launch_bounds__(128) void k_hg(const float* __restrict__ xr,
                                            const float* __restrict__ xi,
                                            float* __restrict__ yr,
                                            float* __restrict__ yi,
                                            const float* __restrict__ wp) {
  const int b = threadIdx.x;
  const int P = blockIdx.x, Q = blockIdx.y;
  int rrow[6], rcol[6];
#pragma unroll
  for (int I = 0; I < 6; ++I) {
    rrow[I] = rp_apply<PERM>(2 * P + I / 3) * 3 + I % 3;
    rcol[I] = rp_apply<PERM>(2 * Q + I / 3) * 3 + I % 3;
  }
  float X[36], Yr[36], Yi[36];
#pragma unroll
  for (int k = 0; k < 36; ++k) { Yr[k] = 0.f; Yi[k] = 0.f; }

  auto loadX = [&](const float* src) {
#pragma unroll
    for (int I = 0; I < 6; ++I)
#pragma unroll
      for (int J = 0; J < 6; ++J)
        X[I * 6 + J] = src[((size_t)(rrow[I] * 192 + rcol[J])) * 128 + b];
  };
  auto term = [&](float* Y, int lm, int rm) {
    const float* Lw = wp + ((size_t)lm * 32 + P) * 36;
    const float* Rw = wp + ((size_t)rm * 32 + Q) * 36;
#pragma unroll
    for (int i = 0; i < 6; ++i) {
      float tk[6];
#pragma unroll
      for (int k = 0; k < 6; ++k) tk[k] = 0.f;
#pragma unroll
      for (int j = 0; j < 6; ++j) {
        float xv = X[i * 6 + j];
#pragma unroll
        for (int k = 0; k < 6; ++k) tk[k] += xv * Rw[j * 6 + k];
      }
#pragma unroll
      for (int o = 0; o < 6; ++o) {
        float lv = Lw[i * 6 + o];
#pragma unroll
        for (int k = 0; k < 6; ++k) Y[o * 6 + k] += lv * tk[k];
      }
    }
  };
  loadX(xr);
  term(Yr, 0, 0); term(Yr, 1, 1); term(Yi, 6, 7); term(Yi, 7, 6);
  loadX(xi);
  term(Yr, 2, 3); term(Yr, 3, 2); term(Yi, 4, 4); term(Yi, 5, 5);
#pragma unroll
  for (int I = 0; I < 6; ++I)
#pragma unroll
    for (int J = 0; J < 6; ++J) {
      size_t off = ((size_t)((P * 6 + I) * 192 + (Q * 6 + J))) * 128 + b;
      yr[off] = Yr[I * 6 + J];
      yi[off] = Yi[I * 6 + J];
    }
}

// ---------------------------------------------------------------------------
// Fused M1+M2+M3+G1.  M1 reads with switch perm; M2/M3/G1 identity.
// Grid (32,32), 128 threads. mp: (3,8,64,3,3), gp: (8,32,6,6) (stage 0).
// ---------------------------------------------------------------------------
__global__ __launch_bounds__(128) void k_mg(const float* __restrict__ xr,
                                            const float* __restrict__ xi,
                                            float* __restrict__ yr,
                                            float* __restrict__ yi,
                                            const float* __restrict__ mp,
                                            const float* __restrict__ gp) {
  const int b = threadIdx.x;
  const int P = blockIdx.x, Q = blockIdx.y;
  float Vr[36], Vi[36];

#pragma unroll
  for (int aa = 0; aa < 2; ++aa)
#pragma unroll
    for (int bb = 0; bb < 2; ++bb) {
      const int p = 2 * P + aa, q = 2 * Q + bb;
      const int prow = rp_apply<3>(p) * 3, pcol = rp_apply<3>(q) * 3;
      float Xr[9], Xi[9];
#pragma unroll
      for (int i = 0; i < 3; ++i)
#pragma unroll
        for (int j = 0; j < 3; ++j) {
          size_t off = ((size_t)((prow + i) * 192 + (pcol + j))) * 128 + b;
          Xr[i * 3 + j] = xr[off];
          Xi[i * 3 + j] = xi[off];
        }
#pragma unroll
      for (int lk = 0; lk < 3; ++lk) {
        const float* wp = mp + (size_t)lk * (8 * 64 * 9);
        float Yr9[9], Yi9[9];
#pragma unroll
        for (int k = 0; k < 9; ++k) { Yr9[k] = Xr[k]; Yi9[k] = Xi[k]; }
        auto termM = [&](float* Y, const float* X, int lm, int rm) {
          const float* Lw = wp + ((size_t)lm * 64 + p) * 9;
          const float* Rw = wp + ((size_t)rm * 64 + q) * 9;
#pragma unroll
          for (int i = 0; i < 3; ++i) {
            float t0 = X[i*3+0] * Rw[0] + X[i*3+1] * Rw[3] + X[i*3+2] * Rw[6];
            float t1 = X[i*3+0] * Rw[1] + X[i*3+1] * Rw[4] + X[i*3+2] * Rw[7];
            float t2 = X[i*3+0] * Rw[2] + X[i*3+1] * Rw[5] + X[i*3+2] * Rw[8];
#pragma unroll
            for (int o = 0; o < 3; ++o) {
              float lv = Lw[i * 3 + o];
              Y[o*3+0] += lv * t0; Y[o*3+1] += lv * t1; Y[o*3+2] += lv * t2;
            }
          }
        };
        termM(Yr9, Xr, 0, 0); termM(Yr9, Xr, 1, 1); termM(Yi9, Xr, 6, 7); termM(Yi9, Xr, 7, 6);
        termM(Yr9, Xi, 2, 3); termM(Yr9, Xi, 3, 2); termM(Yi9, Xi, 4, 4); termM(Yi9, Xi, 5, 5);
#pragma unroll
        for (int k = 0; k < 9; ++k) { Xr[k] = Yr9[k]; Xi[k] = Yi9[k]; }
      }
#pragma unroll
      for (int i = 0; i < 3; ++i)
#pragma unroll
        for (int j = 0; j < 3; ++j) {
          Vr[(3 * aa + i) * 6 + 3 * bb + j] = Xr[i * 3 + j];
          Vi[(3 * aa + i) * 6 + 3 * bb + j] = Xi[i * 3 + j];
        }
    }

  float Yr[36], Yi[36];
#pragma unroll
  for (int k = 0; k < 36; ++k) { Yr[k] = 0.f; Yi[k] = 0.f; }
  auto termH = [&](float* Y, const float* X, int lm, int rm) {
    const float* Lw = gp + ((size_t)lm * 32 + P) * 36;
    const float* Rw = gp + ((size_t)rm * 32 + Q) * 36;
#pragma unroll
    for (int i = 0; i < 6; ++i) {
      float tk[6];
#pragma unroll
      for (int k = 0; k < 6; ++k) tk[k] = 0.f;
#pragma unroll
      for (int j = 0; j < 6; ++j) {
        float xv = X[i * 6 + j];
#pragma unroll
        for (int k = 0; k < 6; ++k) tk[k] += xv * Rw[j * 6 + k];
      }
#pragma unroll
      for (int o = 0; o < 6; ++o) {
        float lv = Lw[i * 6 + o];
#pragma unroll
        for (int k = 0; k < 6; ++k) Y[o * 6 + k] += lv * tk[k];
      }
    }
  };
  termH(Yr, Vr, 0, 0); termH(Yr, Vr, 1, 1); termH(Yi, Vr, 6, 7); termH(Yi, Vr, 7, 6);
  termH(Yr, Vi, 2, 3); termH(Yr, Vi, 3, 2); termH(Yi, Vi, 4, 4); termH(Yi, Vi, 5, 5);

#pragma unroll
  for (int I = 0; I < 6; ++I)
#pragma unroll
    for (int J = 0; J < 6; ++J) {
      size_t off = ((size_t)((P * 6 + I) * 192 + (Q * 6 + J))) * 128 + b;
      yr[off] = Yr[I * 6 + J];
      yi[off] = Yi[I * 6 + J];
    }
}

// ---------------------------------------------------------------------------
// U layer: Sin=3 -> Sout=2, real bf16 output. perm(l=0) on read. Up: (8,64,3,2)
// out ut: (16384, 128) bf16
// ---------------------------------------------------------------------------
__global__ __launch_bounds__(128) void k_u(const float* __restrict__ xr,
                                           const float* __restrict__ xi,
                                           unsigned short* __restrict__ ut,
                                           const float* __restrict__ wp) {
  const int b = threadIdx.x;
  const int p = blockIdx.x, q = blockIdx.y;
  int rrow[3], rcol[3];
#pragma unroll
  for (int i = 0; i < 3; ++i) {
    rrow[i] = rp_apply<6>(p) * 3 + i;
    rcol[i] = rp_apply<6>(q) * 3 + i;
  }
  float X[9], Y[4] = {0.f, 0.f, 0.f, 0.f};
  auto loadX = [&](const float* src) {
#pragma unroll
    for (int i = 0; i < 3; ++i)
#pragma unroll
      for (int j = 0; j < 3; ++j)
        X[i * 3 + j] = src[((size_t)(rrow[i] * 192 + rcol[j])) * 128 + b];
  };
  auto term = [&](int lm, int rm) {
    const float* Lw = wp + ((size_t)lm * 64 + p) * 6;  // (3,2)
    const float* Rw = wp + ((size_t)rm * 64 + q) * 6;
#pragma unroll
    for (int i = 0; i < 3; ++i) {
      float t0 = X[i*3+0] * Rw[0] + X[i*3+1] * Rw[2] + X[i*3+2] * Rw[4];
      float t1 = X[i*3+0] * Rw[1] + X[i*3+1] * Rw[3] + X[i*3+2] * Rw[5];
      Y[0] += Lw[i*2+0] * t0; Y[1] += Lw[i*2+0] * t1;
      Y[2] += Lw[i*2+1] * t0; Y[3] += Lw[i*2+1] * t1;
    }
  };
  loadX(xr); term(0, 0); term(3, 3);
  loadX(xi); term(4, 5); term(7, 6);
#pragma unroll
  for (int o = 0; o < 2; ++o)
#pragma unroll
    for (int k = 0; k < 2; ++k)
      ut[((size_t)((p * 2 + o) * 128 + (q * 2 + k))) * 128 + b] = f2bf(Y[o * 2 + k]);
}

// ---------------------------------------------------------------------------
// Gather + transpose: yg[b][m] = ut[r_index[m]][b]; both bf16. yg (128,16384)
// ---------------------------------------------------------------------------
__global__ __launch_bounds__(256) void k_gather(const unsigned short* __restrict__ ut,
                                                const int* __restrict__ r_index,
                                                unsigned short* __restrict__ yg) {
  __shared__ unsigned short ls[64][130];
  __shared__ int ridx[64];
  const int t = threadIdx.x;
  const int m0 = blockIdx.x * 64;
  if (t < 64) ridx[t] = r_index[m0 + t];
  __syncthreads();
  for (int it = 0; it < 32; ++it) {
    int idx = it * 256 + t;
    int ml = idx >> 7, b = idx & 127;
    ls[ml][b] = ut[(size_t)ridx[ml] * 128 + b];
  }
  __syncthreads();
  int b = t >> 1, half = t & 1;
#pragma unroll
  for (int c = 0; c < 4; ++c) {
    usx8 v;
#pragma unroll
    for (int e = 0; e < 8; ++e) v[e] = ls[half * 32 + c * 8 + e][b];
    *(usx8*)(yg + (size_t)b * 16384 + m0 + half * 32 + c * 8) = v;
  }
}

// ---------------------------------------------------------------------------
// GEMM v2: out[b][c] = sum_k yg[b][k]*cart[c][k].  M=128(b), N=6400(c), K=16384.
// Grid (4 k-chunks, 100 c-tiles of 64).  BK=64 per step, 64 steps per chunk.
// Each cart row consumed in 256B contiguous runs; a c-tile's 4 k-WGs cover the
// row cooperatively.  yg is LLC-resident (4MB).  partial fp32 (4,128,6400).
// ---------------------------------------------------------------------------
#define G2_KC 4
#define G2_STEPS 64   // 4096 / 64
#define G2_PITCH 72

__global__ __launch_bounds__(256) void k_gemm2(const unsigned short* __restrict__ yg,
                                               const float* __restrict__ cart,
                                               float* __restrict__ partial) {
  __shared__ unsigned short As[2][128][G2_PITCH];  // 36.9 KB
  __shared__ unsigned short Bs[2][64][G2_PITCH];   // 18.4 KB
  const int t = threadIdx.x;
  const int lane = t & 63, w = t >> 6;
  const int kc = blockIdx.x;
  const int c0 = blockIdx.y * 64;
  const int k0 = kc * 4096;

  fx4 acc[2][4];
#pragma unroll
  for (int i = 0; i < 2; ++i)
#pragma unroll
    for (int j = 0; j < 4; ++j) acc[i][j] = (fx4)0.f;

  auto ldA = [&](int rep, int kpos) -> usx8 {
    int c = t + rep * 256;  // 0..1023 ; row=c>>3 (128), koff=(c&7)*8
    return *(const usx8*)(yg + (size_t)(c >> 3) * 16384 + kpos + (c & 7) * 8);
  };
  auto stA = [&](int buf, int rep, usx8 v) {
    int c = t + rep * 256;
    *(usx8*)(&As[buf][c >> 3][(c & 7) * 8]) = v;
  };
  auto ldB = [&](int rep, int kpos, fx4* f0, fx4* f1) {
    int c = t + rep * 256;  // 0..511 ; row=c>>3 (64), koff=(c&7)*8 floats
    const float* p = cart + (size_t)(c0 + (c >> 3)) * 16384 + kpos + (c & 7) * 8;
    *f0 = *(const fx4*)p;
    *f1 = *(const fx4*)(p + 4);
  };
  auto stB = [&](int buf, int rep, fx4 f0, fx4 f1) {
    int c = t + rep * 256;
    usx8 v;
    v[0]=f2bf(f0[0]); v[1]=f2bf(f0[1]); v[2]=f2bf(f0[2]); v[3]=f2bf(f0[3]);
    v[4]=f2bf(f1[0]); v[5]=f2bf(f1[1]); v[6]=f2bf(f1[2]); v[7]=f2bf(f1[3]);
    *(usx8*)(&Bs[buf][c >> 3][(c & 7) * 8]) = v;
  };

  { // prologue: stage step 0 into buf 0
    usx8 a0 = ldA(0, k0), a1 = ldA(1, k0), a2 = ldA(2, k0), a3 = ldA(3, k0);
    fx4 b00, b01, b10, b11;
    ldB(0, k0, &b00, &b01); ldB(1, k0, &b10, &b11);
    stA(0, 0, a0); stA(0, 1, a1); stA(0, 2, a2); stA(0, 3, a3);
    stB(0, 0, b00, b01); stB(0, 1, b10, b11);
  }
  __syncthreads();

  for (int s = 0; s < G2_STEPS; ++s) {
    const int cur = s & 1;
    usx8 av[4]; fx4 b00, b01, b10, b11;
    const bool pf = (s + 1 < G2_STEPS);
    if (pf) {
      int kpos = k0 + (s + 1) * 64;
      av[0] = ldA(0, kpos); av[1] = ldA(1, kpos);
      av[2] = ldA(2, kpos); av[3] = ldA(3, kpos);
      ldB(0, kpos, &b00, &b01); ldB(1, kpos, &b10, &b11);
    }
    sx8 af[2][2], bf[4][2];
#pragma unroll
    for (int mi = 0; mi < 2; ++mi)
#pragma unroll
      for (int kk = 0; kk < 2; ++kk)
        af[mi][kk] = *(const sx8*)(&As[cur][w * 32 + mi * 16 + (lane & 15)][kk * 32 + (lane >> 4) * 8]);
#pragma unroll
    for (int ni = 0; ni < 4; ++ni)
#pragma unroll
      for (int kk = 0; kk < 2; ++kk)
        bf[ni][kk] = *(const sx8*)(&Bs[cur][ni * 16 + (lane & 15)][kk * 32 + (lane >> 4) * 8]);
#pragma unroll
    for (int kk = 0; kk < 2; ++kk)
#pragma unroll
      for (int mi = 0; mi < 2; ++mi)
#pragma unroll
        for (int ni = 0; ni < 4; ++ni)
          acc[mi][ni] = __builtin_amdgcn_mfma_f32_16x16x32_bf16(af[mi][kk], bf[ni][kk], acc[mi][ni], 0, 0, 0);
    if (pf) {
      stA(cur ^ 1, 0, av[0]); stA(cur ^ 1, 1, av[1]);
      stA(cur ^ 1, 2, av[2]); stA(cur ^ 1, 3, av[3]);
      stB(cur ^ 1, 0, b00, b01); stB(cur ^ 1, 1, b10, b11);
    }
    __syncthreads();
  }

  // epilogue: partial[kc][b][c]
#pragma unroll
  for (int mi = 0; mi < 2; ++mi) {
    int brow = w * 32 + mi * 16 + (lane >> 4) * 4;
#pragma unroll
    for (int ni = 0; ni < 4; ++ni) {
      int cc = c0 + ni * 16 + (lane & 15);
#pragma unroll
      for (int r = 0; r < 4; ++r)
        partial[((size_t)kc * 128 + brow + r) * 6400 + cc] = acc[mi][ni][r];
    }
  }
}

__global__ __launch_bounds__(256) void k_reduce2(const float* __restrict__ partial,
                                                 float* __restrict__ out) {
  int i = blockIdx.x * 256 + threadIdx.x;   // fx4 index, 204800 total
  fx4 s = (fx4)0.f;
#pragma unroll
  for (int kc = 0; kc < G2_KC; ++kc)
    s += *(const fx4*)(partial + (size_t)kc * 819200 + (size_t)i * 4);
  *(fx4*)(out + (size_t)i * 4) = s;
}

// ---------------------------------------------------------------------------
extern "C" void kernel_launch(void* const* d_in, const int* in_sizes, int n_in,
                              void* d_out, int out_size, void* d_ws, size_t ws_size,
                              hipStream_t stream) {
  const float* x    = (const float*)d_in[0];
  const float* Vp   = (const float*)d_in[1];
  const float* Hp   = (const float*)d_in[2];
  const float* Mp   = (const float*)d_in[3];
  const float* Gp   = (const float*)d_in[4];
  const float* Up   = (const float*)d_in[5];
  const float* cart = (const float*)d_in[6];
  const int*   ridx = (const int*)d_in[7];
  float* out = (float*)d_out;
  float* ws  = (float*)d_ws;

  const size_t PSZ = 4718592;              // 36864*128 floats (18.87 MB)
  float* P0r = ws;
  float* P0i = ws + PSZ;
  float* P1r = ws + 2 * PSZ;
  float* P1i = ws + 3 * PSZ;
  float* xtr = ws + 4 * PSZ;               // dead after k_vh
  float* xti = xtr + 2097152;              // dead after k_vh
  unsigned short* ut = (unsigned short*)(ws + 4 * PSZ);            // reuses xtr (bf16)
  unsigned short* yg = (unsigned short*)(ws + 4 * PSZ + 1048576);  // after ut
  float* partial = ws;                     // 4*819200 fp32 (13 MB), reuses P0r (dead)

  const size_t HSZ = 8 * 32 * 36;

  k_transpose<<<dim3(128, 4), 256, 0, stream>>>(x, xtr, xti);
  k_vh<<<dim3(32, 32), 128, 0, stream>>>(xtr, xti, P0r, P0i, Vp, Hp + 0 * HSZ);
  k_hg<1><<<dim3(32, 32), 128, 0, stream>>>(P0r, P0i, P1r, P1i, Hp + 1 * HSZ);  // perm(l=4)
  k_hg<2><<<dim3(32, 32), 128, 0, stream>>>(P1r, P1i, P0r, P0i, Hp + 2 * HSZ);  // perm(l=3)
  k_mg<<<dim3(32, 32), 128, 0, stream>>>(P0r, P0i, P1r, P1i, Mp, Gp + 0 * HSZ); // switch+M123+G1
  k_hg<4><<<dim3(32, 32), 128, 0, stream>>>(P1r, P1i, P0r, P0i, Gp + 1 * HSZ);  // perm(l=2)
  k_hg<5><<<dim3(32, 32), 128, 0, stream>>>(P0r, P0i, P1r, P1i, Gp + 2 * HSZ);  // perm(l=1)
  k_u<<<dim3(64, 64), 128, 0, stream>>>(P1r, P1i, ut, Up);                      // perm(l=0) inside
  k_gather<<<dim3(256), 256, 0, stream>>>(ut, ridx, yg);
  k_gemm2<<<dim3(G2_KC, 100), 256, 0, stream>>>(yg, cart, partial);
  k_reduce2<<<dim3(800), 256, 0, stream>>>(partial, out);
  (void)in_sizes; (void)n_in; (void)out_size; (void)ws_size;
}